// Round 9
// baseline (235.693 us; speedup 1.0000x reference)
//
#include <hip/hip_runtime.h>

// VQ-VAE quantization. x: [32,64,64,64] fp32, emb: [1024,64] fp32
#define CCH     64
#define HW      4096
#define NPIX    131072
#define KCODES  1024
#define NELEM   (NPIX * CCH)        // 8388608
#define PPB     128                 // pixels per block (32 per wave, rt=2)
#define CK      64                  // codes per LDS chunk (16 chunks)
#define MARGIN_Q 2u                 // ambiguity margin, 1/2048 distance units

typedef _Float16 f16;
typedef __attribute__((ext_vector_type(8))) _Float16 f16x8;
typedef __attribute__((ext_vector_type(4))) float    f32x4;

static __device__ __forceinline__ f32x4 mfma16(f16x8 a, f16x8 b, f32x4 c) {
    return __builtin_amdgcn_mfma_f32_16x16x32_f16(a, b, c, 0, 0, 0);
}
static __device__ __forceinline__ void dma16(void* lds, const void* g) {
    __builtin_amdgcn_global_load_lds(
        (const __attribute__((address_space(1))) unsigned int*)g,
        (__attribute__((address_space(3))) unsigned int*)lds, 16, 0, 0);
}

// ws layout (bytes):
//   [256..4352)       eeb[k] = 2048*||e_k||^2 + 2^20  (1024 f32)
//   [8192..139264)    cbH swizzled fp16-hi codebook (row r, granule g at r*64 + 8*(g^(r&7)))
//   [139264..270336)  cbL fp16-lo, same swizzle
//   [270336..274432)  per-block loss partials (1024 f32)
#define WS_EEB_F   64
#define WS_CBH_B   8192
#define WS_CBL_B   139264
#define WS_PART_F  67584

__global__ __launch_bounds__(256) void vq_prep(
    const float* __restrict__ emb, f16* __restrict__ cbH, f16* __restrict__ cbL,
    float* __restrict__ eeb_g)
{
    const int t = threadIdx.x;
    if (blockIdx.x < 32) {
        const int gid = blockIdx.x * 256 + t;        // 0..8191 granules
        const int row = gid >> 3, gi = gid & 7;
        const float* src = emb + (size_t)row * CCH + gi * 8;
        float4 v0 = *(const float4*)(src);
        float4 v1 = *(const float4*)(src + 4);
        float vv[8] = {v0.x, v0.y, v0.z, v0.w, v1.x, v1.y, v1.z, v1.w};
        f16x8 h, l;
#pragma unroll
        for (int j = 0; j < 8; ++j) {
            f16 hh = (f16)vv[j];
            h[j] = hh;
            l[j] = (f16)(vv[j] - (float)hh);
        }
        const int off = row * 64 + 8 * (gi ^ (row & 7));
        *(f16x8*)(cbH + off) = h;
        *(f16x8*)(cbL + off) = l;
    } else {
        for (int r = t * 4; r < t * 4 + 4; ++r) {
            const float4* row4 = (const float4*)(emb + (size_t)r * CCH);
            float s = 0.f;
#pragma unroll
            for (int i = 0; i < 16; ++i) {
                float4 v = row4[i];
                s = fmaf(v.x, v.x, s); s = fmaf(v.y, v.y, s);
                s = fmaf(v.z, v.z, s); s = fmaf(v.w, v.w, s);
            }
            eeb_g[r] = fmaf(s, 2048.0f, 1048576.0f);
        }
    }
}

__global__ __launch_bounds__(256, 4) void vq_fused(
    const float* __restrict__ x, const float* __restrict__ emb,
    const f16* __restrict__ cbH, const f16* __restrict__ cbL,
    const float* __restrict__ eeb_g,
    float* __restrict__ o, float* __restrict__ idx_out,
    float* __restrict__ partial)
{
    __shared__ __align__(16) char smem[32768];      // 2 x (8K H | 8K L)
    __shared__ float eebl[2][CK];
    __shared__ unsigned buS[PPB];
    __shared__ float wred[4];

    const int t    = threadIdx.x;
    const int lane = t & 63;
    const int w    = t >> 6;               // wave 0..3
    const int col  = lane & 15;
    const int quad = lane >> 4;
    const int sw0  = 8 * (quad ^ (col & 7));   // swizzled granule, chans 0..31
    const int sw1  = sw0 ^ 32;                 // chans 32..63
    const int n0   = blockIdx.x * PPB;
    const int b    = n0 >> 12;
    const int p0   = n0 & 4095;
    const float* xb = x + (size_t)b * (CCH * HW) + p0;

    // wave w stages its 2KB slice of each 8KB H/L region (linear DMA)
    auto stage = [&](int chunk, int bufi) {
        const int k0 = chunk * CK;
        char* lb = smem + bufi * 16384;
        const char* gH = (const char*)cbH + (size_t)k0 * 128 + w * 2048 + lane * 16;
        const char* gL = (const char*)cbL + (size_t)k0 * 128 + w * 2048 + lane * 16;
        char* lH = lb + w * 2048;
        char* lL = lb + 8192 + w * 2048;
        dma16(lH,        gH);
        dma16(lH + 1024, gH + 1024);
        dma16(lL,        gL);
        dma16(lL + 1024, gL + 1024);
        if (t < CK) eebl[bufi][t] = eeb_g[k0 + t];
    };

    stage(0, 0);    // DMA in flight while we build A fragments

    // ---- A fragments straight from global (MFMA A-layout), fp16 hi/lo split ----
    f16x8 aH[2][2], aL[2][2];
#pragma unroll
    for (int rt = 0; rt < 2; ++rt) {
        const int pp = w * 32 + rt * 16 + col;
#pragma unroll
        for (int kc = 0; kc < 2; ++kc) {
            f16x8 h, l;
#pragma unroll
            for (int j = 0; j < 8; ++j) {
                const int c = kc * 32 + quad * 8 + j;
                float zs = -2.0f * xb[(size_t)c * HW + pp];
                f16 hh = (f16)zs;
                h[j] = hh;
                l[j] = (f16)(zs - (float)hh);
            }
            aH[rt][kc] = h;
            aL[rt][kc] = l;
        }
    }

    unsigned best[8], best2[8];
#pragma unroll
    for (int s = 0; s < 8; ++s) { best[s] = 0xFFFFFFFFu; best2[s] = 0xFFFFFFFFu; }

    // ---- K loop: 16 chunks of 64 codes, DMA double-buffered ----
    for (int chunk = 0; chunk < KCODES / CK; ++chunk) {
        const int cur = chunk & 1;
        __syncthreads();                        // chunk's DMA (issued last iter) visible
        if (chunk + 1 < KCODES / CK) stage(chunk + 1, cur ^ 1);

        const f16* bufH = (const f16*)(smem + cur * 16384);
        const f16* bufL = bufH + 4096;
        const int k0 = chunk * CK;

#pragma unroll
        for (int tile = 0; tile < CK / 16; ++tile) {
            const f16* bh = bufH + (tile * 16 + col) * 64;
            const f16* bl = bufL + (tile * 16 + col) * 64;
            f16x8 bH0 = *(const f16x8*)(bh + sw0);
            f16x8 bH1 = *(const f16x8*)(bh + sw1);
            f16x8 bL0 = *(const f16x8*)(bl + sw0);
            f16x8 bL1 = *(const f16x8*)(bl + sw1);
            const float eebc = eebl[cur][tile * 16 + col];
            const unsigned kb = (unsigned)(k0 + tile * 16 + col);
#pragma unroll
            for (int rt = 0; rt < 2; ++rt) {
                f32x4 a4 = {0.f, 0.f, 0.f, 0.f};
                a4 = mfma16(aH[rt][0], bH0, a4);
                a4 = mfma16(aH[rt][1], bH1, a4);
                a4 = mfma16(aL[rt][0], bH0, a4);
                a4 = mfma16(aL[rt][1], bH1, a4);
                a4 = mfma16(aH[rt][0], bL0, a4);
                a4 = mfma16(aH[rt][1], bL1, a4);
#pragma unroll
                for (int r = 0; r < 4; ++r) {
                    float uf = fmaf(a4[r], 2048.0f, eebc);   // in (0, 2^21)
                    unsigned pk = (((unsigned)uf) << 10) | kb;
                    const int s = rt * 4 + r;
                    best2[s] = min(best2[s], max(pk, best[s]));
                    best[s]  = min(best[s], pk);
                }
            }
        }
    }

    // ---- cross-lane argmin reduce over the 16 code-columns ----
#pragma unroll
    for (int d = 1; d < 16; d <<= 1) {
#pragma unroll
        for (int s = 0; s < 8; ++s) {
            unsigned ob  = __shfl_xor(best[s],  d, 64);
            unsigned ob2 = __shfl_xor(best2[s], d, 64);
            best2[s] = min(min(best2[s], ob2), max(best[s], ob));
            best[s]  = min(best[s], ob);
        }
    }
    if (col == 0) {
#pragma unroll
        for (int rt = 0; rt < 2; ++rt)
#pragma unroll
            for (int r = 0; r < 4; ++r) {
                const int s = rt * 4 + r;
                const unsigned bb = best[s];
                const unsigned fl =
                    (((best2[s] >> 10) - (bb >> 10)) < MARGIN_Q) ? 0x80000000u : 0u;
                buS[w * 32 + rt * 16 + quad * 4 + r] = bb | fl;   // C/D row map
            }
    }
    __syncthreads();

    // ---- epilogue: 2 threads per pixel (32 chans each) ----
    float ss = 0.f;
    {
        const int pl = t & 127;                 // pixel in block
        const int cs = (t >> 7) * 32;           // channel half
        const unsigned bidx = buS[pl] & 1023u;
        if ((t >> 7) == 0) idx_out[n0 + pl] = (float)bidx;
        const float4* er4 = (const float4*)(emb + (size_t)bidx * CCH + cs);
        const float* xbt = xb + pl;
        float* ob = o + (size_t)b * (CCH * HW) + p0 + pl;
#pragma unroll
        for (int i = 0; i < 8; ++i) {
            float4 ev = er4[i];
            float evv[4] = {ev.x, ev.y, ev.z, ev.w};
#pragma unroll
            for (int q = 0; q < 4; ++q) {
                const int c = cs + i * 4 + q;
                float xv = xbt[(size_t)c * HW];
                float e  = evv[q];
                ob[(size_t)c * HW] = xv + (e - xv);
                float d = xv - e;
                ss = fmaf(d, d, ss);
            }
        }
    }
    for (int off = 32; off; off >>= 1) ss += __shfl_down(ss, off, 64);

    // ---- per-wave exact fp64 refine of flagged pixels (rare) ----
    unsigned long long flags =
        __ballot((lane < 32) && ((buS[w * 32 + lane] >> 31) != 0u));
    float extra = 0.f;
    while (flags) {
        const int m = __ffsll((long long)flags) - 1;
        flags &= flags - 1;
        const int pp2 = p0 + w * 32 + m;
        const int n   = n0 + w * 32 + m;
        const float zval = x[(size_t)b * (CCH * HW) + (size_t)lane * HW + pp2];
        float zf[CCH];
#pragma unroll
        for (int c = 0; c < CCH; ++c) zf[c] = __shfl(zval, c, 64);

        double bd = 1e300; int bi = 0;
        for (int j = 0; j < 16; ++j) {
            const int k = lane * 16 + j;                  // ascending in-lane
            const float4* er4 = (const float4*)(emb + (size_t)k * CCH);
            double d0 = 0.0, d1 = 0.0;
#pragma unroll
            for (int i = 0; i < 16; ++i) {
                float4 ev = er4[i];
                double t0 = (double)zf[i * 4 + 0] - (double)ev.x;
                double t1 = (double)zf[i * 4 + 1] - (double)ev.y;
                double t2 = (double)zf[i * 4 + 2] - (double)ev.z;
                double t3 = (double)zf[i * 4 + 3] - (double)ev.w;
                d0 = fma(t0, t0, d0); d1 = fma(t1, t1, d1);
                d0 = fma(t2, t2, d0); d1 = fma(t3, t3, d1);
            }
            double d = d0 + d1;
            if (d < bd) { bd = d; bi = k; }
        }
        for (int dlt = 1; dlt < 64; dlt <<= 1) {
            double od = __shfl_xor(bd, dlt, 64);
            int    oi = __shfl_xor(bi, dlt, 64);
            if (od < bd || (od == bd && oi < bi)) { bd = od; bi = oi; }
        }
        const int oldi = (int)(buS[w * 32 + m] & 1023u);
        if (bi != oldi) {
            if (lane == 0) idx_out[n] = (float)bi;
            const float xv = zval;                        // lane == channel
            const float eo = emb[(size_t)oldi * CCH + lane];
            const float en = emb[(size_t)bi   * CCH + lane];
            o[(size_t)b * (CCH * HW) + (size_t)lane * HW + pp2] = xv + (en - xv);
            const float dn = xv - en, dd = xv - eo;
            float delta = dn * dn - dd * dd;
            for (int off = 32; off; off >>= 1) delta += __shfl_down(delta, off, 64);
            extra += delta;                               // lane0's value is used
        }
    }

    if (lane == 0) wred[w] = ss + extra;
    __syncthreads();
    if (t == 0)
        partial[blockIdx.x] = (wred[0] + wred[1]) + (wred[2] + wred[3]);
}

__global__ void vq_fin(const float* __restrict__ partial, float* __restrict__ loss) {
    __shared__ float r[4];
    const int t = threadIdx.x, lane = t & 63, w = t >> 6;
    float s = partial[t] + partial[256 + t] + partial[512 + t] + partial[768 + t];
    for (int off = 32; off; off >>= 1) s += __shfl_down(s, off, 64);
    if (lane == 0) r[w] = s;
    __syncthreads();
    if (t == 0) loss[0] = 1.25f * ((r[0] + r[1]) + (r[2] + r[3])) * (1.0f / (float)NELEM);
}

extern "C" void kernel_launch(void* const* d_in, const int* in_sizes, int n_in,
                              void* d_out, int out_size, void* d_ws, size_t ws_size,
                              hipStream_t stream) {
    const float* x   = (const float*)d_in[0];
    const float* emb = (const float*)d_in[1];
    float* out = (float*)d_out;
    float* wsf = (float*)d_ws;
    char*  wsb = (char*)d_ws;

    float* o_out    = out;                 // [32,64,64,64]
    float* loss_out = out + NELEM;         // scalar
    float* idx_out  = out + NELEM + 1;     // [32,64,64]
    float* eeb_g    = wsf + WS_EEB_F;
    f16*   cbH      = (f16*)(wsb + WS_CBH_B);
    f16*   cbL      = (f16*)(wsb + WS_CBL_B);
    float* part     = wsf + WS_PART_F;

    vq_prep<<<33, 256, 0, stream>>>(emb, cbH, cbL, eeb_g);
    vq_fused<<<NPIX / PPB, 256, 0, stream>>>(x, emb, cbH, cbL, eeb_g,
                                             o_out, idx_out, part);
    vq_fin<<<1, 256, 0, stream>>>(part, loss_out);
}

// Round 10
// 180.547 us; speedup vs baseline: 1.3054x; 1.3054x over previous
//
#include <hip/hip_runtime.h>

// VQ-VAE quantization. x: [32,64,64,64] fp32, emb: [1024,64] fp32
#define CCH     64
#define HW      4096
#define NPIX    131072
#define KCODES  1024
#define NELEM   (NPIX * CCH)        // 8388608
#define MB      256                 // pixels per block (64 per wave, rt=4)
#define CK      64                  // codes per LDS chunk (16 chunks)
#define MARGIN_Q 2u                 // ambiguity margin, 1/2048 distance units

typedef _Float16 f16;
typedef __attribute__((ext_vector_type(8))) _Float16 f16x8;
typedef __attribute__((ext_vector_type(4))) float    f32x4;

static __device__ __forceinline__ f32x4 mfma16(f16x8 a, f16x8 b, f32x4 c) {
    return __builtin_amdgcn_mfma_f32_16x16x32_f16(a, b, c, 0, 0, 0);
}
static __device__ __forceinline__ void dma16(void* lds, const void* g) {
    __builtin_amdgcn_global_load_lds(
        (const __attribute__((address_space(1))) unsigned int*)g,
        (__attribute__((address_space(3))) unsigned int*)lds, 16, 0, 0);
}

// ws layout (bytes):
//   [256..4352)       eeb[k] = 2048*||e_k||^2 + 2^20  (1024 f32)
//   [8192..139264)    cbH swizzled fp16-hi codebook (row r, granule g at r*64 + 8*(g^(r&7)))
//   [139264..270336)  cbL fp16-lo, same swizzle
//   [270336..272384)  per-block loss partials (512 f32)
#define WS_EEB_F   64
#define WS_CBH_B   8192
#define WS_CBL_B   139264
#define WS_PART_F  67584

__global__ __launch_bounds__(256) void vq_prep(
    const float* __restrict__ emb, f16* __restrict__ cbH, f16* __restrict__ cbL,
    float* __restrict__ eeb_g)
{
    const int t = threadIdx.x;
    if (blockIdx.x < 32) {
        const int gid = blockIdx.x * 256 + t;        // 0..8191 granules
        const int row = gid >> 3, gi = gid & 7;
        const float* src = emb + (size_t)row * CCH + gi * 8;
        float4 v0 = *(const float4*)(src);
        float4 v1 = *(const float4*)(src + 4);
        float vv[8] = {v0.x, v0.y, v0.z, v0.w, v1.x, v1.y, v1.z, v1.w};
        f16x8 h, l;
#pragma unroll
        for (int j = 0; j < 8; ++j) {
            f16 hh = (f16)vv[j];
            h[j] = hh;
            l[j] = (f16)(vv[j] - (float)hh);
        }
        const int off = row * 64 + 8 * (gi ^ (row & 7));
        *(f16x8*)(cbH + off) = h;
        *(f16x8*)(cbL + off) = l;
    } else {
        for (int r = t * 4; r < t * 4 + 4; ++r) {
            const float4* row4 = (const float4*)(emb + (size_t)r * CCH);
            float s = 0.f;
#pragma unroll
            for (int i = 0; i < 16; ++i) {
                float4 v = row4[i];
                s = fmaf(v.x, v.x, s); s = fmaf(v.y, v.y, s);
                s = fmaf(v.z, v.z, s); s = fmaf(v.w, v.w, s);
            }
            eeb_g[r] = fmaf(s, 2048.0f, 1048576.0f);
        }
    }
}

__global__ __launch_bounds__(256, 2) void vq_fused(
    const float* __restrict__ x, const float* __restrict__ emb,
    const f16* __restrict__ cbH, const f16* __restrict__ cbL,
    const float* __restrict__ eeb_g,
    float* __restrict__ o, float* __restrict__ idx_out,
    float* __restrict__ partial)
{
    __shared__ __align__(16) char smem[32768];      // 2 x (8K H | 8K L)
    __shared__ float eebl[2][CK];
    __shared__ unsigned buS[MB];
    __shared__ float wred[4];

    const int t    = threadIdx.x;
    const int lane = t & 63;
    const int w    = t >> 6;               // wave 0..3
    const int col  = lane & 15;
    const int quad = lane >> 4;
    const int sw0  = 8 * (quad ^ (col & 7));   // swizzled granule, chans 0..31
    const int sw1  = sw0 ^ 32;                 // chans 32..63
    const int n0   = blockIdx.x * MB;
    const int b    = n0 >> 12;
    const int p0   = n0 & 4095;
    const float* xb = x + (size_t)b * (CCH * HW) + p0;

    // wave w stages its 2KB slice of each 8KB H/L region (linear DMA)
    auto stage = [&](int chunk, int bufi) {
        const int k0 = chunk * CK;
        char* lb = smem + bufi * 16384;
        const char* gH = (const char*)cbH + (size_t)k0 * 128 + w * 2048 + lane * 16;
        const char* gL = (const char*)cbL + (size_t)k0 * 128 + w * 2048 + lane * 16;
        char* lH = lb + w * 2048;
        char* lL = lb + 8192 + w * 2048;
        dma16(lH,        gH);
        dma16(lH + 1024, gH + 1024);
        dma16(lL,        gL);
        dma16(lL + 1024, gL + 1024);
        if (t < CK) eebl[bufi][t] = eeb_g[k0 + t];
    };

    stage(0, 0);    // DMA in flight while we build A fragments

    // ---- A fragments straight from global (MFMA A-layout), fp16 hi/lo split ----
    f16x8 aH[4][2], aL[4][2];
#pragma unroll
    for (int rt = 0; rt < 4; ++rt) {
        const int pp = w * 64 + rt * 16 + col;
#pragma unroll
        for (int kc = 0; kc < 2; ++kc) {
            f16x8 h, l;
#pragma unroll
            for (int j = 0; j < 8; ++j) {
                const int c = kc * 32 + quad * 8 + j;
                float zs = -2.0f * xb[(size_t)c * HW + pp];
                f16 hh = (f16)zs;
                h[j] = hh;
                l[j] = (f16)(zs - (float)hh);
            }
            aH[rt][kc] = h;
            aL[rt][kc] = l;
        }
    }

    unsigned best[16], best2[16];
#pragma unroll
    for (int s = 0; s < 16; ++s) { best[s] = 0xFFFFFFFFu; best2[s] = 0xFFFFFFFFu; }

    // ---- K loop: 16 chunks of 64 codes, DMA double-buffered ----
    for (int chunk = 0; chunk < KCODES / CK; ++chunk) {
        const int cur = chunk & 1;
        __syncthreads();                        // this chunk's DMA visible
        if (chunk + 1 < KCODES / CK) stage(chunk + 1, cur ^ 1);

        const f16* bufH = (const f16*)(smem + cur * 16384);
        const f16* bufL = bufH + 4096;
        const int k0 = chunk * CK;

#pragma unroll
        for (int tile = 0; tile < CK / 16; ++tile) {
            const f16* bh = bufH + (tile * 16 + col) * 64;
            const f16* bl = bufL + (tile * 16 + col) * 64;
            f16x8 bH0 = *(const f16x8*)(bh + sw0);
            f16x8 bH1 = *(const f16x8*)(bh + sw1);
            f16x8 bL0 = *(const f16x8*)(bl + sw0);
            f16x8 bL1 = *(const f16x8*)(bl + sw1);
            const float eebc = eebl[cur][tile * 16 + col];
            const unsigned kb = (unsigned)(k0 + tile * 16 + col);
#pragma unroll
            for (int rt = 0; rt < 4; ++rt) {
                f32x4 a4 = {0.f, 0.f, 0.f, 0.f};
                a4 = mfma16(aH[rt][0], bH0, a4);
                a4 = mfma16(aH[rt][1], bH1, a4);
                a4 = mfma16(aL[rt][0], bH0, a4);
                a4 = mfma16(aL[rt][1], bH1, a4);
                a4 = mfma16(aH[rt][0], bL0, a4);
                a4 = mfma16(aH[rt][1], bL1, a4);
#pragma unroll
                for (int r = 0; r < 4; ++r) {
                    const int s = rt * 4 + r;
                    float uf = fmaf(a4[r], 2048.0f, eebc);   // in (0, 2^21)
                    // forced selection: cvt + lshl_or + max + 2x min (6 VALU total)
                    unsigned pk, mx;
                    asm("v_cvt_u32_f32 %0, %1" : "=v"(pk) : "v"(uf));
                    asm("v_lshl_or_b32 %0, %0, 10, %1" : "+v"(pk) : "v"(kb));
                    asm("v_max_u32 %0, %1, %2" : "=v"(mx) : "v"(pk), "v"(best[s]));
                    asm("v_min_u32 %0, %0, %1" : "+v"(best2[s]) : "v"(mx));
                    asm("v_min_u32 %0, %0, %1" : "+v"(best[s]) : "v"(pk));
                }
            }
        }
    }

    // ---- cross-lane argmin reduce over the 16 code-columns ----
#pragma unroll
    for (int d = 1; d < 16; d <<= 1) {
#pragma unroll
        for (int s = 0; s < 16; ++s) {
            unsigned ob  = __shfl_xor(best[s],  d, 64);
            unsigned ob2 = __shfl_xor(best2[s], d, 64);
            unsigned mx;
            asm("v_max_u32 %0, %1, %2" : "=v"(mx) : "v"(best[s]), "v"(ob));
            asm("v_min_u32 %0, %0, %1" : "+v"(ob2) : "v"(mx));
            asm("v_min_u32 %0, %0, %1" : "+v"(best2[s]) : "v"(ob2));
            asm("v_min_u32 %0, %0, %1" : "+v"(best[s]) : "v"(ob));
        }
    }
    if (col == 0) {
#pragma unroll
        for (int rt = 0; rt < 4; ++rt)
#pragma unroll
            for (int r = 0; r < 4; ++r) {
                const int s = rt * 4 + r;
                const unsigned bb = best[s];
                const unsigned fl =
                    (((best2[s] >> 10) - (bb >> 10)) < MARGIN_Q) ? 0x80000000u : 0u;
                buS[w * 64 + rt * 16 + quad * 4 + r] = bb | fl;   // C/D row map
            }
    }
    __syncthreads();

    // ---- epilogue: one pixel per thread ----
    const unsigned bu = buS[t];
    const unsigned bidx = bu & 1023u;
    idx_out[n0 + t] = (float)bidx;
    float ss = 0.f;
    {
        const float4* er4 = (const float4*)(emb + (size_t)bidx * CCH);
        const float* xbt = xb + t;
        float* ob = o + (size_t)b * (CCH * HW) + p0 + t;
#pragma unroll
        for (int i = 0; i < 16; ++i) {
            float4 ev = er4[i];
            float evv[4] = {ev.x, ev.y, ev.z, ev.w};
#pragma unroll
            for (int q = 0; q < 4; ++q) {
                const int c = i * 4 + q;
                float xv = xbt[(size_t)c * HW];
                float e  = evv[q];
                ob[(size_t)c * HW] = xv + (e - xv);
                float d = xv - e;
                ss = fmaf(d, d, ss);
            }
        }
    }
    for (int off = 32; off; off >>= 1) ss += __shfl_down(ss, off, 64);

    // ---- per-wave exact fp64 refine of flagged pixels (rare, ~0.2%) ----
    unsigned long long flags = __ballot((buS[w * 64 + lane] >> 31) != 0u);
    float extra = 0.f;
    while (flags) {
        const int m = __ffsll((long long)flags) - 1;
        flags &= flags - 1;
        const int pp2 = p0 + w * 64 + m;
        const int n   = n0 + w * 64 + m;
        const float zval = x[(size_t)b * (CCH * HW) + (size_t)lane * HW + pp2];
        float zf[CCH];
#pragma unroll
        for (int c = 0; c < CCH; ++c) zf[c] = __shfl(zval, c, 64);

        double bd = 1e300; int bi = 0;
        for (int j = 0; j < 16; ++j) {
            const int k = lane * 16 + j;                  // ascending in-lane
            const float4* er4 = (const float4*)(emb + (size_t)k * CCH);
            double d0 = 0.0, d1 = 0.0;
#pragma unroll
            for (int i = 0; i < 16; ++i) {
                float4 ev = er4[i];
                double t0 = (double)zf[i * 4 + 0] - (double)ev.x;
                double t1 = (double)zf[i * 4 + 1] - (double)ev.y;
                double t2 = (double)zf[i * 4 + 2] - (double)ev.z;
                double t3 = (double)zf[i * 4 + 3] - (double)ev.w;
                d0 = fma(t0, t0, d0); d1 = fma(t1, t1, d1);
                d0 = fma(t2, t2, d0); d1 = fma(t3, t3, d1);
            }
            double d = d0 + d1;
            if (d < bd) { bd = d; bi = k; }
        }
        for (int dlt = 1; dlt < 64; dlt <<= 1) {
            double od = __shfl_xor(bd, dlt, 64);
            int    oi = __shfl_xor(bi, dlt, 64);
            if (od < bd || (od == bd && oi < bi)) { bd = od; bi = oi; }
        }
        const int oldi = (int)(buS[w * 64 + m] & 1023u);
        if (bi != oldi) {
            if (lane == 0) idx_out[n] = (float)bi;
            const float xv = zval;                        // lane == channel
            const float eo = emb[(size_t)oldi * CCH + lane];
            const float en = emb[(size_t)bi   * CCH + lane];
            o[(size_t)b * (CCH * HW) + (size_t)lane * HW + pp2] = xv + (en - xv);
            const float dn = xv - en, dd = xv - eo;
            float delta = dn * dn - dd * dd;
            for (int off = 32; off; off >>= 1) delta += __shfl_down(delta, off, 64);
            extra += delta;                               // lane0's value is used
        }
    }

    if (lane == 0) wred[w] = ss + extra;
    __syncthreads();
    if (t == 0)
        partial[blockIdx.x] = (wred[0] + wred[1]) + (wred[2] + wred[3]);
}

__global__ void vq_fin(const float* __restrict__ partial, float* __restrict__ loss) {
    __shared__ float r[4];
    const int t = threadIdx.x, lane = t & 63, w = t >> 6;
    float s = partial[t] + partial[256 + t];
    for (int off = 32; off; off >>= 1) s += __shfl_down(s, off, 64);
    if (lane == 0) r[w] = s;
    __syncthreads();
    if (t == 0) loss[0] = 1.25f * ((r[0] + r[1]) + (r[2] + r[3])) * (1.0f / (float)NELEM);
}

extern "C" void kernel_launch(void* const* d_in, const int* in_sizes, int n_in,
                              void* d_out, int out_size, void* d_ws, size_t ws_size,
                              hipStream_t stream) {
    const float* x   = (const float*)d_in[0];
    const float* emb = (const float*)d_in[1];
    float* out = (float*)d_out;
    float* wsf = (float*)d_ws;
    char*  wsb = (char*)d_ws;

    float* o_out    = out;                 // [32,64,64,64]
    float* loss_out = out + NELEM;         // scalar
    float* idx_out  = out + NELEM + 1;     // [32,64,64]
    float* eeb_g    = wsf + WS_EEB_F;
    f16*   cbH      = (f16*)(wsb + WS_CBH_B);
    f16*   cbL      = (f16*)(wsb + WS_CBL_B);
    float* part     = wsf + WS_PART_F;

    vq_prep<<<33, 256, 0, stream>>>(emb, cbH, cbL, eeb_g);
    vq_fused<<<NPIX / MB, 256, 0, stream>>>(x, emb, cbH, cbL, eeb_g,
                                            o_out, idx_out, part);
    vq_fin<<<1, 256, 0, stream>>>(part, loss_out);
}